// Round 10
// baseline (439.691 us; speedup 1.0000x reference)
//
#include <hip/hip_runtime.h>

#define A_DIM 6
#define HID_D 64
#define LATENT_D 64
#define GRU_IN_D 134
#define T_STEPS 128
#define N_ENV 10
#define BN_TOT 640

typedef float f2 __attribute__((ext_vector_type(2)));

// Pre-scaled transcendentals: log2e factors folded into weights/invariants.
//   sig_pre(x)  == sigmoid(t) where x = -log2(e) * t
//   tanh_pre(y) == tanh(t)    where y =  2*log2(e) * t
#define KSIG (-1.4426950408889634f)
#define KTANH (2.8853900817779268f)
__device__ __forceinline__ float sig_pre(float x) {
    return __builtin_amdgcn_rcpf(1.0f + __builtin_amdgcn_exp2f(x));
}
__device__ __forceinline__ float tanh_pre(float y) {
    return fmaf(-2.0f, __builtin_amdgcn_rcpf(1.0f + __builtin_amdgcn_exp2f(y)), 1.0f);
}

template<int CTRL>
__device__ __forceinline__ float dppadd(float v) {
    int t = __builtin_amdgcn_update_dpp(0, __builtin_bit_cast(int, v), CTRL, 0xf, 0xf, true);
    return v + __builtin_bit_cast(float, t);
}
// sum over all 64 lanes -> wave-uniform scalar (VALU pipe only)
__device__ __forceinline__ float wave_reduce_add(float v) {
    v = dppadd<0x111>(v);   // row_shr:1
    v = dppadd<0x112>(v);   // row_shr:2
    v = dppadd<0x114>(v);   // row_shr:4
    v = dppadd<0x118>(v);   // row_shr:8
    v = dppadd<0x142>(v);   // row_bcast:15
    v = dppadd<0x143>(v);   // row_bcast:31 -> lane 63 has total
    return __builtin_bit_cast(float, __builtin_amdgcn_readlane(__builtin_bit_cast(int, v), 63));
}

__global__ __launch_bounds__(128, 1)
void policy_kernel(const float* __restrict__ s_h,
                   const int*   __restrict__ a_h,
                   const float* __restrict__ b_z,
                   const float* __restrict__ conv1_w, const float* __restrict__ conv1_b,
                   const float* __restrict__ conv2_w, const float* __restrict__ conv2_b,
                   const float* __restrict__ fc_w,    const float* __restrict__ fc_b,
                   const float* __restrict__ emb,
                   const float* __restrict__ gru_wih, const float* __restrict__ gru_whh,
                   const float* __restrict__ gru_bih, const float* __restrict__ gru_bhh,
                   const float* __restrict__ mlp1_w,  const float* __restrict__ mlp1_b,
                   const float* __restrict__ mlp2_w,  const float* __restrict__ mlp2_b,
                   float* __restrict__ logits_out, float* __restrict__ mask_out)
{
    __shared__ __align__(16) float s0[512];      // frame0 [c][h][w]
    __shared__ __align__(16) float a1[1152];     // conv1 out [32][36]
    __shared__ __align__(16) float a2[512];      // conv2 out flat
    __shared__ __align__(16) float pfc[128];     // fc partials
    __shared__ __align__(16) float semb[64];
    __shared__ __align__(16) float gxc[192];     // step-invariant gx (+biases)
    __shared__ __align__(16) float atab[6*192];  // per-action gx contribution
    __shared__ __align__(16) float h_lds[64];    // current h broadcast buffer
    __shared__ __align__(16) float llog[(T_STEPS-1)*A_DIM];  // logits buffer (762)

    const int bn  = blockIdx.x;          // 0..639
    const int tid = threadIdx.x;         // 0..127 (preamble); rollout = wave 0 only
    const int j   = tid & 63;
    const int w   = tid >> 6;

    // ---- masks output ----
    mask_out[bn * T_STEPS + tid] = (a_h[bn * T_STEPS + tid] != (A_DIM - 1)) ? 1.0f : 0.0f;

    // ---- load frame 0 ----
    {
        const float* src = s_h + (size_t)bn * T_STEPS * 512;
        #pragma unroll
        for (int i = 0; i < 4; ++i) s0[tid + i * 128] = src[tid + i * 128];
    }
    __syncthreads();

    // ---- conv1: (8,8,8) -> (32,6,6), ReLU ----
    for (int i = tid; i < 1152; i += 128) {
        const int oc = i / 36, r = i % 36, oh = r / 6, ow = r % 6;
        float sum = conv1_b[oc];
        const float* wp = conv1_w + oc * 72;
        #pragma unroll
        for (int ic = 0; ic < 8; ++ic)
            #pragma unroll
            for (int kh = 0; kh < 3; ++kh)
                #pragma unroll
                for (int kw = 0; kw < 3; ++kw)
                    sum = fmaf(s0[ic * 64 + (oh + kh) * 8 + (ow + kw)],
                               wp[ic * 9 + kh * 3 + kw], sum);
        a1[i] = fmaxf(sum, 0.0f);
    }
    __syncthreads();

    // ---- conv2: (32,6,6) -> (32,4,4), ReLU ----
    for (int i = tid; i < 512; i += 128) {
        const int oc = i / 16, r = i % 16, oh = r / 4, ow = r % 4;
        float sum = conv2_b[oc];
        const float* wp = conv2_w + oc * 288;
        for (int ic = 0; ic < 32; ++ic)
            #pragma unroll
            for (int kh = 0; kh < 3; ++kh)
                #pragma unroll
                for (int kw = 0; kw < 3; ++kw)
                    sum = fmaf(a1[ic * 36 + (oh + kh) * 6 + (ow + kw)],
                               wp[ic * 9 + kh * 3 + kw], sum);
        a2[i] = fmaxf(sum, 0.0f);
    }
    __syncthreads();

    // ---- fc: 512 -> 64, ReLU (k-split across 2 waves) ----
    {
        const float* wp = fc_w + j * 512 + w * 256;
        const float* ap = a2 + w * 256;
        float s0a = 0.f, s1a = 0.f, s2a = 0.f, s3a = 0.f;
        for (int k = 0; k < 256; k += 4) {
            s0a = fmaf(ap[k + 0], wp[k + 0], s0a);
            s1a = fmaf(ap[k + 1], wp[k + 1], s1a);
            s2a = fmaf(ap[k + 2], wp[k + 2], s2a);
            s3a = fmaf(ap[k + 3], wp[k + 3], s3a);
        }
        pfc[tid] = (s0a + s1a) + (s2a + s3a);
    }
    __syncthreads();
    if (tid < 64) semb[tid] = fmaxf(pfc[tid] + pfc[tid + 64] + fc_b[tid], 0.0f);
    __syncthreads();

    // ---- step-invariant gx ----
    {
        const float* bz = b_z + (size_t)(bn / N_ENV) * LATENT_D;
        for (int g = tid; g < 192; g += 128) {
            float sum = gru_bih[g] + ((g < 128) ? gru_bhh[g] : 0.0f);
            const float* wp = gru_wih + g * GRU_IN_D;
            for (int k = 0; k < 64; ++k) sum = fmaf(semb[k], wp[k], sum);
            for (int k = 0; k < 64; ++k) sum = fmaf(bz[k], wp[70 + k], sum);
            gxc[g] = sum;
        }
    }
    // ---- action table ----
    for (int i = tid; i < 6 * 192; i += 128) {
        const int a = i / 192, g = i % 192;
        float sum = 0.0f;
        #pragma unroll
        for (int q = 0; q < 6; ++q)
            sum = fmaf(emb[a * 6 + q], gru_wih[g * GRU_IN_D + 64 + q], sum);
        atab[i] = sum;
    }
    __syncthreads();

    if (w == 1) return;   // rollout is single-wave; wave 1 exits

    // ---- per-lane fp32 weights, PRE-SCALED by the transcendental constants:
    //      wr,wz * KSIG (feed sigmoid args); wn,w1 * KTANH (feed tanh args)
    f2 wr[32], wz[32], wn[32], w1[32];
    {
        const float* pr = gru_whh + (size_t)j * 64;
        const float* pz = gru_whh + (size_t)(64 + j) * 64;
        const float* pn = gru_whh + (size_t)(128 + j) * 64;
        const float* p1 = mlp1_w + (size_t)j * 64;
        #pragma unroll
        for (int i = 0; i < 16; ++i) {
            float4 v;
            v = ((const float4*)pr)[i];
            wr[2*i] = (f2){KSIG*v.x, KSIG*v.y}; wr[2*i+1] = (f2){KSIG*v.z, KSIG*v.w};
            v = ((const float4*)pz)[i];
            wz[2*i] = (f2){KSIG*v.x, KSIG*v.y}; wz[2*i+1] = (f2){KSIG*v.z, KSIG*v.w};
            v = ((const float4*)pn)[i];
            wn[2*i] = (f2){KTANH*v.x, KTANH*v.y}; wn[2*i+1] = (f2){KTANH*v.z, KTANH*v.w};
            v = ((const float4*)p1)[i];
            w1[2*i] = (f2){KTANH*v.x, KTANH*v.y}; w1[2*i+1] = (f2){KTANH*v.z, KTANH*v.w};
        }
    }
    const float bhn_s = KTANH * gru_bhh[128 + j];   // scaled n-gate bias
    const float b1s   = KTANH * mlp1_b[j];          // scaled mlp1 bias

    // step-invariant per-action gate inputs (pre-scaled) + mlp2 coefs.
    // b2 folded into the reduction leaf: b2s = b2[a] at lane 0 only.
    float arx[6], azx[6], anx[6], m2c[6], b2s[6];
    {
        const float gxr = gxc[j], gxz = gxc[64 + j], gxn = gxc[128 + j];
        #pragma unroll
        for (int a = 0; a < 6; ++a) {
            arx[a] = KSIG  * (gxr + atab[a * 192 + j]);
            azx[a] = KSIG  * (gxz + atab[a * 192 + 64 + j]);
            anx[a] = KTANH * (gxn + atab[a * 192 + 128 + j]);
            m2c[a] = mlp2_w[a * 64 + j];
            b2s[a] = (j == 0) ? mlp2_b[a] : 0.0f;
        }
    }

    // ---- seed: h_1 = GRU(h_0 = 0, act = 5): hr = hz = 0, hn = bhn_s ----
    float hprev;
    {
        const float r = sig_pre(arx[5]);
        const float z = sig_pre(azx[5]);
        const float n = tanh_pre(fmaf(r, bhn_s, anx[5]));
        hprev = fmaf(z, 0.0f - n, n);            // (1-z)*n + z*0
    }
    __builtin_amdgcn_wave_barrier();
    h_lds[j] = hprev;
    __builtin_amdgcn_wave_barrier();

    for (int t = 0; t < T_STEPS - 1; ++t) {
        // ---- batched broadcast load of h (uniform addresses, one wait) ----
        const float4* hb = (const float4*)h_lds;
        float4 h00 = hb[0],  h01 = hb[1],  h02 = hb[2],  h03 = hb[3];
        float4 h04 = hb[4],  h05 = hb[5],  h06 = hb[6],  h07 = hb[7];
        float4 h08 = hb[8],  h09 = hb[9],  h10 = hb[10], h11 = hb[11];
        float4 h12 = hb[12], h13 = hb[13], h14 = hb[14], h15 = hb[15];
        __builtin_amdgcn_sched_barrier(0);

        // ---- fused sweep, 4-way chains everywhere (dep depth 8) ----
        f2 p1a = {0.f,0.f}, p1b = {0.f,0.f}, p1c = {0.f,0.f}, p1d = {0.f,0.f};
        f2 pra = {0.f,0.f}, prb = {0.f,0.f}, prc = {0.f,0.f}, prd = {0.f,0.f};
        f2 pza = {0.f,0.f}, pzb = {0.f,0.f}, pzc = {0.f,0.f}, pzd = {0.f,0.f};
        f2 pna = {0.f,0.f}, pnb = {0.f,0.f}, pnc = {0.f,0.f}, pnd = {0.f,0.f};
        #define SWEEPA(i, hv) { \
            const f2 haa = (f2){hv.x, hv.y}; \
            const f2 hcc = (f2){hv.z, hv.w}; \
            p1a += haa * w1[2*(i)]; p1b += hcc * w1[2*(i)+1]; \
            pra += haa * wr[2*(i)]; prb += hcc * wr[2*(i)+1]; \
            pza += haa * wz[2*(i)]; pzb += hcc * wz[2*(i)+1]; \
            pna += haa * wn[2*(i)]; pnb += hcc * wn[2*(i)+1]; }
        #define SWEEPB(i, hv) { \
            const f2 haa = (f2){hv.x, hv.y}; \
            const f2 hcc = (f2){hv.z, hv.w}; \
            p1c += haa * w1[2*(i)]; p1d += hcc * w1[2*(i)+1]; \
            prc += haa * wr[2*(i)]; prd += hcc * wr[2*(i)+1]; \
            pzc += haa * wz[2*(i)]; pzd += hcc * wz[2*(i)+1]; \
            pnc += haa * wn[2*(i)]; pnd += hcc * wn[2*(i)+1]; }
        SWEEPA(0,  h00) SWEEPA(1,  h01) SWEEPA(2,  h02) SWEEPA(3,  h03)
        SWEEPA(4,  h04) SWEEPA(5,  h05) SWEEPA(6,  h06) SWEEPA(7,  h07)
        SWEEPB(8,  h08) SWEEPB(9,  h09) SWEEPB(10, h10) SWEEPB(11, h11)
        SWEEPB(12, h12) SWEEPB(13, h13) SWEEPB(14, h14) SWEEPB(15, h15)
        #undef SWEEPA
        #undef SWEEPB
        const f2 p1 = (p1a + p1b) + (p1c + p1d);
        const float hid = tanh_pre(p1.x + p1.y + b1s);
        const f2 prf = (pra + prb) + (prc + prd);
        const f2 pzf = (pza + pzb) + (pzc + pzd);
        const f2 pnf = (pna + pnb) + (pnc + pnd);
        const float hr = prf.x + prf.y;               // pre-scaled (sigmoid arg)
        const float hz = pzf.x + pzf.y;               // pre-scaled (sigmoid arg)
        const float hn = pnf.x + pnf.y + bhn_s;       // pre-scaled (tanh arg)

        // ---- mlp2 via DPP wave reduction; b2 folded into the leaf ----
        const float l0 = wave_reduce_add(fmaf(hid, m2c[0], b2s[0]));
        const float l1 = wave_reduce_add(fmaf(hid, m2c[1], b2s[1]));
        const float l2 = wave_reduce_add(fmaf(hid, m2c[2], b2s[2]));
        const float l3 = wave_reduce_add(fmaf(hid, m2c[3], b2s[3]));
        const float l4 = wave_reduce_add(fmaf(hid, m2c[4], b2s[4]));
        const float l5 = wave_reduce_add(fmaf(hid, m2c[5], b2s[5]));

        // ---- argmax tree (first-max-wins) carrying selected pre-scaled gates
        const bool c01 = l1 > l0;
        const float m01 = c01 ? l1 : l0;
        float sr = c01 ? arx[1] : arx[0];
        float sz = c01 ? azx[1] : azx[0];
        float sn = c01 ? anx[1] : anx[0];
        const bool c23 = l3 > l2;
        const float m23 = c23 ? l3 : l2;
        const float sr23 = c23 ? arx[3] : arx[2];
        const float sz23 = c23 ? azx[3] : azx[2];
        const float sn23 = c23 ? anx[3] : anx[2];
        const bool c45 = l5 > l4;
        const float m45 = c45 ? l5 : l4;
        const float sr45 = c45 ? arx[5] : arx[4];
        const float sz45 = c45 ? azx[5] : azx[4];
        const float sn45 = c45 ? anx[5] : anx[4];
        const bool cA = m23 > m01;
        const float mA = cA ? m23 : m01;
        sr = cA ? sr23 : sr;
        sz = cA ? sz23 : sz;
        sn = cA ? sn23 : sn;
        const bool cB = m45 > mA;
        sr = cB ? sr45 : sr;
        sz = cB ? sz45 : sz;
        sn = cB ? sn45 : sn;

        // ---- single-action gates for the chosen action (pre-scaled args) ----
        const float r = sig_pre(sr + hr);
        const float z = sig_pre(sz + hz);
        const float n = tanh_pre(fmaf(r, hn, sn));
        const float hnew = fmaf(z, hprev - n, n);

        // ---- h write FIRST (starts the DS pipe), llog rides its latency ----
        __builtin_amdgcn_wave_barrier();
        h_lds[j] = hnew;
        hprev = hnew;
        if (j < A_DIM) {
            const float outv = (j == 0) ? l0 : (j == 1) ? l1 : (j == 2) ? l2
                             : (j == 3) ? l3 : (j == 4) ? l4 : l5;
            llog[t * A_DIM + j] = outv;
        }
        __builtin_amdgcn_wave_barrier();
    }

    // ---- flush logits LDS -> global (coalesced, once) ----
    {
        float* lout = logits_out + (size_t)bn * (T_STEPS - 1) * A_DIM;
        for (int i = j; i < (T_STEPS - 1) * A_DIM; i += 64) lout[i] = llog[i];
    }
}

extern "C" void kernel_launch(void* const* d_in, const int* in_sizes, int n_in,
                              void* d_out, int out_size, void* d_ws, size_t ws_size,
                              hipStream_t stream) {
    const float* s_h     = (const float*)d_in[0];
    const int*   a_h     = (const int*)  d_in[1];
    const float* b_z     = (const float*)d_in[2];
    const float* conv1_w = (const float*)d_in[3];
    const float* conv1_b = (const float*)d_in[4];
    const float* conv2_w = (const float*)d_in[5];
    const float* conv2_b = (const float*)d_in[6];
    const float* fc_w    = (const float*)d_in[7];
    const float* fc_b    = (const float*)d_in[8];
    const float* emb     = (const float*)d_in[9];
    const float* gru_wih = (const float*)d_in[10];
    const float* gru_whh = (const float*)d_in[11];
    const float* gru_bih = (const float*)d_in[12];
    const float* gru_bhh = (const float*)d_in[13];
    const float* mlp1_w  = (const float*)d_in[14];
    const float* mlp1_b  = (const float*)d_in[15];
    const float* mlp2_w  = (const float*)d_in[16];
    const float* mlp2_b  = (const float*)d_in[17];

    float* out = (float*)d_out;
    float* logits_out = out;                                          // (B,N,127,6)
    float* mask_out   = out + (size_t)BN_TOT * (T_STEPS - 1) * A_DIM; // (B,N,128,1)

    policy_kernel<<<BN_TOT, 128, 0, stream>>>(
        s_h, a_h, b_z, conv1_w, conv1_b, conv2_w, conv2_b, fc_w, fc_b, emb,
        gru_wih, gru_whh, gru_bih, gru_bhh, mlp1_w, mlp1_b, mlp2_w, mlp2_b,
        logits_out, mask_out);
}